// Round 1
// baseline (5666.340 us; speedup 1.0000x reference)
//
#include <hip/hip_runtime.h>
#include <hip/hip_bf16.h>

// 2-layer GCN: h1 = x@W1 -> sym-norm scatter (16-wide) -> relu(+self+b1)
//            -> sym-norm scatter of h1r (16-wide; W2 commutes with the sum)
//            -> (agg2+self)@W2 + b2 fused with sorted-batch sum pooling.
// Workspace layout (floats): dinv[N] | h1[N*16] | agg1[N*16] | h1r[N*16] | agg2[N*16]

#define TPB 256

__global__ void deg_kernel(const int* __restrict__ col, float* __restrict__ deg, int E) {
    int e = blockIdx.x * blockDim.x + threadIdx.x;
    if (e < E) atomicAdd(&deg[col[e]], 1.0f);
}

__global__ void dinv_kernel(float* __restrict__ dinv, int N) {
    int i = blockIdx.x * blockDim.x + threadIdx.x;
    if (i < N) dinv[i] = rsqrtf(dinv[i] + 1.0f);   // +1 = self loop
}

// h1[n][k] = sum_c x[n][c] * W1[c][k]   (N x 128) @ (128 x 16)
__global__ __launch_bounds__(TPB) void gemm1_kernel(const float* __restrict__ x,
                                                    const float* __restrict__ W1,
                                                    float* __restrict__ h1, int N) {
    __shared__ float w1s[128 * 16];
    __shared__ float xs[16 * 132];   // 16 rows, stride 132 to break bank aliasing
    int t = threadIdx.x;
    for (int i = t; i < 128 * 16; i += TPB) w1s[i] = W1[i];

    int n0 = blockIdx.x * 16;
    // stage 16 rows of x (512 float4), coalesced
    const float4* xv = (const float4*)(x + (size_t)n0 * 128);
    int rows = min(16, N - n0);
    for (int f = t; f < rows * 32; f += TPB) {
        int nl = f >> 5, ci = f & 31;
        float4 v = xv[f];
        float* dst = &xs[nl * 132 + ci * 4];
        dst[0] = v.x; dst[1] = v.y; dst[2] = v.z; dst[3] = v.w;
    }
    __syncthreads();

    int nl = t >> 4, k = t & 15;
    int n = n0 + nl;
    if (n >= N) return;
    const float* xr = &xs[nl * 132];
    float acc = 0.f;
#pragma unroll 8
    for (int c = 0; c < 128; ++c) acc = fmaf(xr[c], w1s[c * 16 + k], acc);
    h1[(size_t)n * 16 + k] = acc;
}

// agg[c] += h[r] * dinv[r]*dinv[c], one thread per edge, 16-wide payload
__global__ void scatter16_kernel(const int* __restrict__ row, const int* __restrict__ col,
                                 const float* __restrict__ dinv, const float* __restrict__ h,
                                 float* __restrict__ agg, int E) {
    int e = blockIdx.x * blockDim.x + threadIdx.x;
    if (e >= E) return;
    int r = row[e], c = col[e];
    float w = dinv[r] * dinv[c];
    const float4* hv = (const float4*)(h + (size_t)r * 16);
    float4 a = hv[0], b = hv[1], cc = hv[2], d = hv[3];
    float* o = agg + (size_t)c * 16;
    atomicAdd(o + 0,  a.x * w);  atomicAdd(o + 1,  a.y * w);
    atomicAdd(o + 2,  a.z * w);  atomicAdd(o + 3,  a.w * w);
    atomicAdd(o + 4,  b.x * w);  atomicAdd(o + 5,  b.y * w);
    atomicAdd(o + 6,  b.z * w);  atomicAdd(o + 7,  b.w * w);
    atomicAdd(o + 8,  cc.x * w); atomicAdd(o + 9,  cc.y * w);
    atomicAdd(o + 10, cc.z * w); atomicAdd(o + 11, cc.w * w);
    atomicAdd(o + 12, d.x * w);  atomicAdd(o + 13, d.y * w);
    atomicAdd(o + 14, d.z * w);  atomicAdd(o + 15, d.w * w);
}

// h1r = relu(agg1 + h1*dinv^2 + b1), processed as float4 groups (N*4 of them)
__global__ void relu_self_kernel(const float* __restrict__ agg1, const float* __restrict__ h1,
                                 const float* __restrict__ dinv, const float* __restrict__ b1,
                                 float* __restrict__ h1r, int N) {
    int i = blockIdx.x * blockDim.x + threadIdx.x;
    if (i >= N * 4) return;
    int n = i >> 2, q = i & 3;
    float dv = dinv[n];
    float d2 = dv * dv;
    float4 a = ((const float4*)agg1)[i];
    float4 h = ((const float4*)h1)[i];
    float4 bb = ((const float4*)b1)[q];
    float4 r;
    r.x = fmaxf(fmaf(h.x, d2, a.x) + bb.x, 0.f);
    r.y = fmaxf(fmaf(h.y, d2, a.y) + bb.y, 0.f);
    r.z = fmaxf(fmaf(h.z, d2, a.z) + bb.z, 0.f);
    r.w = fmaxf(fmaf(h.w, d2, a.w) + bb.w, 0.f);
    ((float4*)h1r)[i] = r;
}

// out[g][k] += sum over nodes n (batch sorted): ((agg2[n]+h1r[n]*dinv^2) @ W2)[k] + b2[k]
// One wave per 16 consecutive nodes; register run-accumulator flushed on graph change.
__global__ __launch_bounds__(TPB) void final_kernel(const float* __restrict__ agg2,
                                                    const float* __restrict__ h1r,
                                                    const float* __restrict__ dinv,
                                                    const float* __restrict__ W2,
                                                    const float* __restrict__ b2,
                                                    const int* __restrict__ batch,
                                                    float* __restrict__ out, int N) {
    __shared__ float w2s[16 * 64];
    int t = threadIdx.x;
    for (int i = t; i < 16 * 64; i += TPB) w2s[i] = W2[i];
    __syncthreads();

    int wave = t >> 6, lane = t & 63;
    int n0 = blockIdx.x * 64 + wave * 16;
    float b2k = b2[lane];
    int g_cur = -1;
    float acc = 0.f;
    for (int i = 0; i < 16; ++i) {
        int n = n0 + i;
        if (n >= N) break;
        float dv = dinv[n];
        float d2 = dv * dv;
        const float4* av = (const float4*)(agg2 + (size_t)n * 16);
        const float4* hv = (const float4*)(h1r + (size_t)n * 16);
        float v[16];
#pragma unroll
        for (int q = 0; q < 4; ++q) {
            float4 a = av[q], h = hv[q];
            v[q * 4 + 0] = fmaf(h.x, d2, a.x);
            v[q * 4 + 1] = fmaf(h.y, d2, a.y);
            v[q * 4 + 2] = fmaf(h.z, d2, a.z);
            v[q * 4 + 3] = fmaf(h.w, d2, a.w);
        }
        float val = b2k;
#pragma unroll
        for (int j = 0; j < 16; ++j) val = fmaf(v[j], w2s[j * 64 + lane], val);
        int g = batch[n];
        if (g != g_cur) {
            if (g_cur >= 0) atomicAdd(&out[(size_t)g_cur * 64 + lane], acc);
            acc = 0.f;
            g_cur = g;
        }
        acc += val;
    }
    if (g_cur >= 0) atomicAdd(&out[(size_t)g_cur * 64 + lane], acc);
}

extern "C" void kernel_launch(void* const* d_in, const int* in_sizes, int n_in,
                              void* d_out, int out_size, void* d_ws, size_t ws_size,
                              hipStream_t stream) {
    const float* x     = (const float*)d_in[0];
    const int*   ei    = (const int*)d_in[1];
    const int*   batch = (const int*)d_in[2];
    const float* W1    = (const float*)d_in[3];
    const float* b1    = (const float*)d_in[4];
    const float* W2    = (const float*)d_in[5];
    const float* b2    = (const float*)d_in[6];

    const int N = in_sizes[0] / 128;
    const int E = in_sizes[1] / 2;
    const int* row = ei;        // edge_index[0]
    const int* col = ei + E;    // edge_index[1]

    float* ws   = (float*)d_ws;
    float* dinv = ws;                         // N      (deg, then dinv in place)
    float* h1   = dinv + N;                   // N*16
    float* agg1 = h1   + (size_t)N * 16;      // N*16
    float* h1r  = agg1 + (size_t)N * 16;      // N*16
    float* agg2 = h1r  + (size_t)N * 16;      // N*16
    float* out  = (float*)d_out;

    hipMemsetAsync(dinv, 0, (size_t)N * sizeof(float), stream);
    hipMemsetAsync(agg1, 0, (size_t)N * 16 * sizeof(float), stream);
    hipMemsetAsync(agg2, 0, (size_t)N * 16 * sizeof(float), stream);
    hipMemsetAsync(out,  0, (size_t)out_size * sizeof(float), stream);

    deg_kernel<<<(E + TPB - 1) / TPB, TPB, 0, stream>>>(col, dinv, E);
    dinv_kernel<<<(N + TPB - 1) / TPB, TPB, 0, stream>>>(dinv, N);
    gemm1_kernel<<<(N + 15) / 16, TPB, 0, stream>>>(x, W1, h1, N);
    scatter16_kernel<<<(E + TPB - 1) / TPB, TPB, 0, stream>>>(row, col, dinv, h1, agg1, E);
    relu_self_kernel<<<(N * 4 + TPB - 1) / TPB, TPB, 0, stream>>>(agg1, h1, dinv, b1, h1r, N);
    scatter16_kernel<<<(E + TPB - 1) / TPB, TPB, 0, stream>>>(row, col, dinv, h1r, agg2, E);
    final_kernel<<<(N + 63) / 64, TPB, 0, stream>>>(agg2, h1r, dinv, W2, b2, batch, out, N);
}

// Round 2
// 707.282 us; speedup vs baseline: 8.0114x; 8.0114x over previous
//
#include <hip/hip_runtime.h>
#include <hip/hip_bf16.h>

// 2-layer GCN via CSR-gather (no fp32 atomics in the hot path):
//   deg histogram -> 3-kernel exclusive scan -> bucket fill (src, weight)
//   h1 = x@W1 ; agg1 = gather(h1) ; h1r = relu(agg1 + self + b1)
//   agg2 = gather(h1r) ; out = pool((agg2 + self)@W2 + b2)  [W2 commutes with sum]
// Round-1 lesson: fp32 atomicAdd is memory-side on gfx950 (32B HBM write-through
// per atomic; WRITE_SIZE showed 1.6GB/dispatch) -> scatter was 93% of runtime.

#define TPB 256

__global__ void deg_kernel(const int* __restrict__ col, int* __restrict__ deg, int E) {
    int e = blockIdx.x * blockDim.x + threadIdx.x;
    if (e < E) atomicAdd(&deg[col[e]], 1);
}

// block-level exclusive scan of deg; bsum[b] = block total
__global__ __launch_bounds__(TPB) void scan1_kernel(const int* __restrict__ deg,
                                                    int* __restrict__ offs,
                                                    int* __restrict__ bsum, int N) {
    __shared__ int s[TPB];
    int t = threadIdx.x;
    int i = blockIdx.x * TPB + t;
    int d = (i < N) ? deg[i] : 0;
    s[t] = d; __syncthreads();
    for (int off = 1; off < TPB; off <<= 1) {
        int v = (t >= off) ? s[t - off] : 0;
        __syncthreads();
        s[t] += v;
        __syncthreads();
    }
    if (i < N) offs[i] = s[t] - d;           // exclusive within block
    if (t == TPB - 1) bsum[blockIdx.x] = s[t];
}

// single-block exclusive scan of block sums (nb <= 1024)
__global__ __launch_bounds__(1024) void scan2_kernel(int* __restrict__ bsum, int nb) {
    __shared__ int s[1024];
    int t = threadIdx.x;
    int v = (t < nb) ? bsum[t] : 0;
    s[t] = v; __syncthreads();
    for (int off = 1; off < 1024; off <<= 1) {
        int u = (t >= off) ? s[t - off] : 0;
        __syncthreads();
        s[t] += u;
        __syncthreads();
    }
    if (t < nb) bsum[t] = s[t] - v;          // exclusive
}

// finalize offsets, init cursors, compute dinv
__global__ __launch_bounds__(TPB) void scan3_kernel(int* __restrict__ offs,
                                                    const int* __restrict__ bsum,
                                                    int* __restrict__ cursor,
                                                    const int* __restrict__ deg,
                                                    float* __restrict__ dinv, int N, int E) {
    int i = blockIdx.x * TPB + threadIdx.x;
    if (i < N) {
        int o = offs[i] + bsum[blockIdx.x];
        offs[i] = o;
        cursor[i] = o;
        dinv[i] = rsqrtf((float)deg[i] + 1.0f);   // +1 = self loop
    }
    if (i == 0) offs[N] = E;
}

// csr[slot] = (src, dinv[src]*dinv[dst])
__global__ void fill_kernel(const int* __restrict__ row, const int* __restrict__ col,
                            const float* __restrict__ dinv, int* __restrict__ cursor,
                            int2* __restrict__ csr, int E) {
    int e = blockIdx.x * blockDim.x + threadIdx.x;
    if (e >= E) return;
    int r = row[e], c = col[e];
    int slot = atomicAdd(&cursor[c], 1);
    csr[slot] = make_int2(r, __float_as_int(dinv[r] * dinv[c]));
}

// h1[n][k] = sum_c x[n][c] * W1[c][k]   (N x 128) @ (128 x 16)
__global__ __launch_bounds__(TPB) void gemm1_kernel(const float* __restrict__ x,
                                                    const float* __restrict__ W1,
                                                    float* __restrict__ h1, int N) {
    __shared__ float w1s[128 * 16];
    __shared__ float xs[16 * 132];
    int t = threadIdx.x;
    for (int i = t; i < 128 * 16; i += TPB) w1s[i] = W1[i];

    int n0 = blockIdx.x * 16;
    const float4* xv = (const float4*)(x + (size_t)n0 * 128);
    int rows = min(16, N - n0);
    for (int f = t; f < rows * 32; f += TPB) {
        int nl = f >> 5, ci = f & 31;
        float4 v = xv[f];
        float* dst = &xs[nl * 132 + ci * 4];
        dst[0] = v.x; dst[1] = v.y; dst[2] = v.z; dst[3] = v.w;
    }
    __syncthreads();

    int nl = t >> 4, k = t & 15;
    int n = n0 + nl;
    if (n >= N) return;
    const float* xr = &xs[nl * 132];
    float acc = 0.f;
#pragma unroll 8
    for (int c = 0; c < 128; ++c) acc = fmaf(xr[c], w1s[c * 16 + k], acc);
    h1[(size_t)n * 16 + k] = acc;
}

// agg[c][k] = sum over in-edges of c: w_e * h[src_e][k].  16 lanes per dest.
__global__ __launch_bounds__(TPB) void gather_kernel(const int2* __restrict__ csr,
                                                     const int* __restrict__ offs,
                                                     const float* __restrict__ h,
                                                     float* __restrict__ agg, int N) {
    int t = threadIdx.x;
    int c = blockIdx.x * 16 + (t >> 4);
    int k = t & 15;
    if (c >= N) return;
    int p = offs[c], e2 = offs[c + 1];
    float acc = 0.f;
    // unroll-by-2 to keep two loads in flight
    for (; p + 1 < e2; p += 2) {
        int2 sw0 = csr[p], sw1 = csr[p + 1];
        float v0 = h[(size_t)sw0.x * 16 + k];
        float v1 = h[(size_t)sw1.x * 16 + k];
        acc = fmaf(__int_as_float(sw0.y), v0, acc);
        acc = fmaf(__int_as_float(sw1.y), v1, acc);
    }
    if (p < e2) {
        int2 sw = csr[p];
        acc = fmaf(__int_as_float(sw.y), h[(size_t)sw.x * 16 + k], acc);
    }
    agg[(size_t)c * 16 + k] = acc;
}

// h1r = relu(agg1 + h1*dinv^2 + b1)
__global__ void relu_self_kernel(const float* __restrict__ agg1, const float* __restrict__ h1,
                                 const float* __restrict__ dinv, const float* __restrict__ b1,
                                 float* __restrict__ h1r, int N) {
    int i = blockIdx.x * blockDim.x + threadIdx.x;
    if (i >= N * 4) return;
    int n = i >> 2, q = i & 3;
    float dv = dinv[n];
    float d2 = dv * dv;
    float4 a = ((const float4*)agg1)[i];
    float4 h = ((const float4*)h1)[i];
    float4 bb = ((const float4*)b1)[q];
    float4 r;
    r.x = fmaxf(fmaf(h.x, d2, a.x) + bb.x, 0.f);
    r.y = fmaxf(fmaf(h.y, d2, a.y) + bb.y, 0.f);
    r.z = fmaxf(fmaf(h.z, d2, a.z) + bb.z, 0.f);
    r.w = fmaxf(fmaf(h.w, d2, a.w) + bb.w, 0.f);
    ((float4*)h1r)[i] = r;
}

// out[g] += ((agg2[n]+h1r[n]*dinv^2) @ W2 + b2), pooled over sorted batch runs
__global__ __launch_bounds__(TPB) void final_kernel(const float* __restrict__ agg2,
                                                    const float* __restrict__ h1r,
                                                    const float* __restrict__ dinv,
                                                    const float* __restrict__ W2,
                                                    const float* __restrict__ b2,
                                                    const int* __restrict__ batch,
                                                    float* __restrict__ out, int N) {
    __shared__ float w2s[16 * 64];
    int t = threadIdx.x;
    for (int i = t; i < 16 * 64; i += TPB) w2s[i] = W2[i];
    __syncthreads();

    int wave = t >> 6, lane = t & 63;
    int n0 = blockIdx.x * 64 + wave * 16;
    float b2k = b2[lane];
    int g_cur = -1;
    float acc = 0.f;
    for (int i = 0; i < 16; ++i) {
        int n = n0 + i;
        if (n >= N) break;
        float dv = dinv[n];
        float d2 = dv * dv;
        const float4* av = (const float4*)(agg2 + (size_t)n * 16);
        const float4* hv = (const float4*)(h1r + (size_t)n * 16);
        float v[16];
#pragma unroll
        for (int q = 0; q < 4; ++q) {
            float4 a = av[q], h = hv[q];
            v[q * 4 + 0] = fmaf(h.x, d2, a.x);
            v[q * 4 + 1] = fmaf(h.y, d2, a.y);
            v[q * 4 + 2] = fmaf(h.z, d2, a.z);
            v[q * 4 + 3] = fmaf(h.w, d2, a.w);
        }
        float val = b2k;
#pragma unroll
        for (int j = 0; j < 16; ++j) val = fmaf(v[j], w2s[j * 64 + lane], val);
        int g = batch[n];
        if (g != g_cur) {
            if (g_cur >= 0) atomicAdd(&out[(size_t)g_cur * 64 + lane], acc);
            acc = 0.f;
            g_cur = g;
        }
        acc += val;
    }
    if (g_cur >= 0) atomicAdd(&out[(size_t)g_cur * 64 + lane], acc);
}

extern "C" void kernel_launch(void* const* d_in, const int* in_sizes, int n_in,
                              void* d_out, int out_size, void* d_ws, size_t ws_size,
                              hipStream_t stream) {
    const float* x     = (const float*)d_in[0];
    const int*   ei    = (const int*)d_in[1];
    const int*   batch = (const int*)d_in[2];
    const float* W1    = (const float*)d_in[3];
    const float* b1    = (const float*)d_in[4];
    const float* W2    = (const float*)d_in[5];
    const float* b2    = (const float*)d_in[6];

    const int N = in_sizes[0] / 128;
    const int E = in_sizes[1] / 2;
    const int* row = ei;        // edge_index[0]
    const int* col = ei + E;    // edge_index[1]
    const int NB = (N + TPB - 1) / TPB;      // 782 for N=200000 (<=1024 required)

    char* p = (char*)d_ws;
    float* dinv   = (float*)p;  p += (size_t)N * 4;
    int*   deg    = (int*)p;    p += (size_t)N * 4;
    int*   offs   = (int*)p;    p += (size_t)(N + 1) * 4;
    int*   cursor = (int*)p;    p += (size_t)N * 4;
    int*   bsum   = (int*)p;    p += 1024 * 4;
    int2*  csr    = (int2*)p;   p += (size_t)E * 8;
    float* h1     = (float*)p;  p += (size_t)N * 16 * 4;
    float* agg1   = (float*)p;  p += (size_t)N * 16 * 4;
    float* h1r    = (float*)p;  p += (size_t)N * 16 * 4;
    float* agg2   = h1;                      // h1 dead after relu_self
    float* out    = (float*)d_out;

    hipMemsetAsync(deg, 0, (size_t)N * sizeof(int), stream);
    hipMemsetAsync(out, 0, (size_t)out_size * sizeof(float), stream);

    deg_kernel<<<(E + TPB - 1) / TPB, TPB, 0, stream>>>(col, deg, E);
    scan1_kernel<<<NB, TPB, 0, stream>>>(deg, offs, bsum, N);
    scan2_kernel<<<1, 1024, 0, stream>>>(bsum, NB);
    scan3_kernel<<<NB, TPB, 0, stream>>>(offs, bsum, cursor, deg, dinv, N, E);
    fill_kernel<<<(E + TPB - 1) / TPB, TPB, 0, stream>>>(row, col, dinv, cursor, csr, E);
    gemm1_kernel<<<(N + 15) / 16, TPB, 0, stream>>>(x, W1, h1, N);
    gather_kernel<<<(N + 15) / 16, TPB, 0, stream>>>(csr, offs, h1, agg1, N);
    relu_self_kernel<<<(N * 4 + TPB - 1) / TPB, TPB, 0, stream>>>(agg1, h1, dinv, b1, h1r, N);
    gather_kernel<<<(N + 15) / 16, TPB, 0, stream>>>(csr, offs, h1r, agg2, N);
    final_kernel<<<(N + 63) / 64, TPB, 0, stream>>>(agg2, h1r, dinv, W2, b2, batch, out, N);
}

// Round 3
// 610.483 us; speedup vs baseline: 9.2817x; 1.1586x over previous
//
#include <hip/hip_runtime.h>
#include <hip/hip_bf16.h>

// 2-layer GCN, CSR-gather, minimal atomics.
//   rank[e]=atomicAdd(deg[col],1)  (the ONLY per-edge atomic pass)
//   scan(deg)->offs,dinv ; csr[offs[c]+rank[e]]=row[e]  (atomic-free fill)
//   h1' = dinv*(x@W1)                       [gemm1: 1 thread/node, scalar W]
//   h2' = dinv*relu(dinv*(gather(h1')+h1'self)+b1)   [fused]
//   a2  = dinv*(gather(h2')+h2'self)
//   out = pool(a2@W2+b2) over sorted batch  [64 nodes/wave to cut flush atomics]
// Round-1/2 lesson: global atomics ~19K/us device-wide (memory-side, ~1/cyc/XCD);
// fp32 scatter and double atomic passes are the enemy.

#define TPB 256

__global__ void rank_kernel(const int* __restrict__ col, int* __restrict__ deg,
                            int* __restrict__ rank, int E) {
    int e = blockIdx.x * blockDim.x + threadIdx.x;
    if (e < E) rank[e] = atomicAdd(&deg[col[e]], 1);
}

// block-level exclusive scan of deg; bsum[b] = block total
__global__ __launch_bounds__(TPB) void scan1_kernel(const int* __restrict__ deg,
                                                    int* __restrict__ offs,
                                                    int* __restrict__ bsum, int N) {
    __shared__ int s[TPB];
    int t = threadIdx.x;
    int i = blockIdx.x * TPB + t;
    int d = (i < N) ? deg[i] : 0;
    s[t] = d; __syncthreads();
    for (int off = 1; off < TPB; off <<= 1) {
        int v = (t >= off) ? s[t - off] : 0;
        __syncthreads();
        s[t] += v;
        __syncthreads();
    }
    if (i < N) offs[i] = s[t] - d;           // exclusive within block
    if (t == TPB - 1) bsum[blockIdx.x] = s[t];
}

// single-block exclusive scan of block sums (nb <= 1024)
__global__ __launch_bounds__(1024) void scan2_kernel(int* __restrict__ bsum, int nb) {
    __shared__ int s[1024];
    int t = threadIdx.x;
    int v = (t < nb) ? bsum[t] : 0;
    s[t] = v; __syncthreads();
    for (int off = 1; off < 1024; off <<= 1) {
        int u = (t >= off) ? s[t - off] : 0;
        __syncthreads();
        s[t] += u;
        __syncthreads();
    }
    if (t < nb) bsum[t] = s[t] - v;          // exclusive
}

// finalize offsets, compute dinv
__global__ __launch_bounds__(TPB) void scan3_kernel(int* __restrict__ offs,
                                                    const int* __restrict__ bsum,
                                                    const int* __restrict__ deg,
                                                    float* __restrict__ dinv, int N, int E) {
    int i = blockIdx.x * TPB + threadIdx.x;
    if (i < N) {
        offs[i] += bsum[blockIdx.x];
        dinv[i] = rsqrtf((float)deg[i] + 1.0f);   // +1 = self loop
    }
    if (i == 0) offs[N] = E;
}

// csr[offs[c] + rank[e]] = row[e]   (no atomics)
__global__ void fill_kernel(const int* __restrict__ row, const int* __restrict__ col,
                            const int* __restrict__ rank, const int* __restrict__ offs,
                            int* __restrict__ csr, int E) {
    int e = blockIdx.x * blockDim.x + threadIdx.x;
    if (e >= E) return;
    int c = col[e];
    csr[offs[c] + rank[e]] = row[e];
}

// h1'[n] = dinv[n] * (x[n] @ W1).  One thread per node, 16 accumulators.
// x streamed in 64B line groups; W1 indices are wave-uniform -> scalar loads.
__global__ __launch_bounds__(TPB) void gemm1_kernel(const float* __restrict__ x,
                                                    const float* __restrict__ W1,
                                                    const float* __restrict__ dinv,
                                                    float* __restrict__ h1p, int N) {
    int n = blockIdx.x * TPB + threadIdx.x;
    if (n >= N) return;
    const float4* xr = (const float4*)(x + (size_t)n * 128);
    float acc[16];
#pragma unroll
    for (int k = 0; k < 16; ++k) acc[k] = 0.f;
#pragma unroll 1
    for (int g = 0; g < 8; ++g) {            // 16 cols = one 64B line of x per group
        float4 v0 = xr[g * 4 + 0], v1 = xr[g * 4 + 1];
        float4 v2 = xr[g * 4 + 2], v3 = xr[g * 4 + 3];
        float xv[16] = {v0.x, v0.y, v0.z, v0.w, v1.x, v1.y, v1.z, v1.w,
                        v2.x, v2.y, v2.z, v2.w, v3.x, v3.y, v3.z, v3.w};
#pragma unroll
        for (int cc = 0; cc < 16; ++cc) {
            const float4* w4 = (const float4*)(W1 + (size_t)(g * 16 + cc) * 16);
            float4 wa = w4[0], wb = w4[1], wc = w4[2], wd = w4[3];
            float xc = xv[cc];
            acc[0]  = fmaf(xc, wa.x, acc[0]);  acc[1]  = fmaf(xc, wa.y, acc[1]);
            acc[2]  = fmaf(xc, wa.z, acc[2]);  acc[3]  = fmaf(xc, wa.w, acc[3]);
            acc[4]  = fmaf(xc, wb.x, acc[4]);  acc[5]  = fmaf(xc, wb.y, acc[5]);
            acc[6]  = fmaf(xc, wb.z, acc[6]);  acc[7]  = fmaf(xc, wb.w, acc[7]);
            acc[8]  = fmaf(xc, wc.x, acc[8]);  acc[9]  = fmaf(xc, wc.y, acc[9]);
            acc[10] = fmaf(xc, wc.z, acc[10]); acc[11] = fmaf(xc, wc.w, acc[11]);
            acc[12] = fmaf(xc, wd.x, acc[12]); acc[13] = fmaf(xc, wd.y, acc[13]);
            acc[14] = fmaf(xc, wd.z, acc[14]); acc[15] = fmaf(xc, wd.w, acc[15]);
        }
    }
    float dv = dinv[n];
    float4* o = (float4*)(h1p + (size_t)n * 16);
    o[0] = make_float4(acc[0] * dv, acc[1] * dv, acc[2] * dv, acc[3] * dv);
    o[1] = make_float4(acc[4] * dv, acc[5] * dv, acc[6] * dv, acc[7] * dv);
    o[2] = make_float4(acc[8] * dv, acc[9] * dv, acc[10] * dv, acc[11] * dv);
    o[3] = make_float4(acc[12] * dv, acc[13] * dv, acc[14] * dv, acc[15] * dv);
}

// h2'[c] = dinv[c]*relu(dinv[c]*(sum_{e->c} h1'[src] + h1'[c]) + b1)
// 16 lanes per dest; csr read coalesced in 16-chunks, shfl-broadcast -> 16 loads in flight
__global__ __launch_bounds__(TPB) void gather1_kernel(const int* __restrict__ csr,
                                                      const int* __restrict__ offs,
                                                      const float* __restrict__ h1p,
                                                      const float* __restrict__ dinv,
                                                      const float* __restrict__ b1,
                                                      float* __restrict__ h2p, int N) {
    int t = threadIdx.x;
    int c = blockIdx.x * 16 + (t >> 4);
    int k = t & 15;
    if (c >= N) return;
    int p1 = offs[c + 1];
    float acc = 0.f;
    for (int p = offs[c]; p < p1; p += 16) {
        int idx = p + k;
        int s = (idx < p1) ? csr[idx] : -1;
#pragma unroll
        for (int j = 0; j < 16; ++j) {
            int sj = __shfl(s, j, 16);
            if (sj >= 0) acc += h1p[(size_t)sj * 16 + k];
        }
    }
    float dc = dinv[c];
    float a = fmaf(dc, acc + h1p[(size_t)c * 16 + k], b1[k]);
    h2p[(size_t)c * 16 + k] = dc * fmaxf(a, 0.f);
}

// a2[c] = dinv[c]*(sum_{e->c} h2'[src] + h2'[c])
__global__ __launch_bounds__(TPB) void gather2_kernel(const int* __restrict__ csr,
                                                      const int* __restrict__ offs,
                                                      const float* __restrict__ h2p,
                                                      const float* __restrict__ dinv,
                                                      float* __restrict__ a2, int N) {
    int t = threadIdx.x;
    int c = blockIdx.x * 16 + (t >> 4);
    int k = t & 15;
    if (c >= N) return;
    int p1 = offs[c + 1];
    float acc = 0.f;
    for (int p = offs[c]; p < p1; p += 16) {
        int idx = p + k;
        int s = (idx < p1) ? csr[idx] : -1;
#pragma unroll
        for (int j = 0; j < 16; ++j) {
            int sj = __shfl(s, j, 16);
            if (sj >= 0) acc += h2p[(size_t)sj * 16 + k];
        }
    }
    a2[(size_t)c * 16 + k] = dinv[c] * (acc + h2p[(size_t)c * 16 + k]);
}

// out[g] += a2[n]@W2 + b2, pooled over sorted batch; 64 nodes per wave
__global__ __launch_bounds__(TPB) void final_kernel(const float* __restrict__ a2,
                                                    const float* __restrict__ W2,
                                                    const float* __restrict__ b2,
                                                    const int* __restrict__ batch,
                                                    float* __restrict__ out, int N) {
    __shared__ float w2s[16 * 64];
    int t = threadIdx.x;
    for (int i = t; i < 16 * 64; i += TPB) w2s[i] = W2[i];
    __syncthreads();

    int wave = t >> 6, lane = t & 63;
    int n0 = blockIdx.x * 256 + wave * 64;
    float b2k = b2[lane];
    int g_cur = -1;
    float acc = 0.f;
    for (int i = 0; i < 64; ++i) {
        int n = n0 + i;
        if (n >= N) break;
        const float* ar = a2 + (size_t)n * 16;
        float val = b2k;
#pragma unroll
        for (int j = 0; j < 16; ++j) val = fmaf(ar[j], w2s[j * 64 + lane], val);
        int g = batch[n];
        if (g != g_cur) {
            if (g_cur >= 0) atomicAdd(&out[(size_t)g_cur * 64 + lane], acc);
            acc = 0.f;
            g_cur = g;
        }
        acc += val;
    }
    if (g_cur >= 0) atomicAdd(&out[(size_t)g_cur * 64 + lane], acc);
}

extern "C" void kernel_launch(void* const* d_in, const int* in_sizes, int n_in,
                              void* d_out, int out_size, void* d_ws, size_t ws_size,
                              hipStream_t stream) {
    const float* x     = (const float*)d_in[0];
    const int*   ei    = (const int*)d_in[1];
    const int*   batch = (const int*)d_in[2];
    const float* W1    = (const float*)d_in[3];
    const float* b1    = (const float*)d_in[4];
    const float* W2    = (const float*)d_in[5];
    const float* b2    = (const float*)d_in[6];

    const int N = in_sizes[0] / 128;
    const int E = in_sizes[1] / 2;
    const int* row = ei;        // edge_index[0]
    const int* col = ei + E;    // edge_index[1]
    const int NB = (N + TPB - 1) / TPB;      // 782 for N=200000 (<=1024 required)

    char* p = (char*)d_ws;
    float* dinv = (float*)p;  p += (size_t)N * 4;
    int*   deg  = (int*)p;    p += (size_t)N * 4;
    int*   offs = (int*)p;    p += (size_t)(N + 1) * 4;
    int*   bsum = (int*)p;    p += 1024 * 4;
    int*   rank = (int*)p;    p += (size_t)E * 4;
    int*   csr  = (int*)p;    p += (size_t)E * 4;
    float* h1p  = (float*)p;  p += (size_t)N * 16 * 4;
    float* h2p  = (float*)p;  p += (size_t)N * 16 * 4;
    float* a2   = h1p;                        // h1p dead after gather1
    float* out  = (float*)d_out;

    hipMemsetAsync(deg, 0, (size_t)N * sizeof(int), stream);
    hipMemsetAsync(out, 0, (size_t)out_size * sizeof(float), stream);

    rank_kernel<<<(E + TPB - 1) / TPB, TPB, 0, stream>>>(col, deg, rank, E);
    scan1_kernel<<<NB, TPB, 0, stream>>>(deg, offs, bsum, N);
    scan2_kernel<<<1, 1024, 0, stream>>>(bsum, NB);
    scan3_kernel<<<NB, TPB, 0, stream>>>(offs, bsum, deg, dinv, N, E);
    fill_kernel<<<(E + TPB - 1) / TPB, TPB, 0, stream>>>(row, col, rank, offs, csr, E);
    gemm1_kernel<<<NB, TPB, 0, stream>>>(x, W1, dinv, h1p, N);
    gather1_kernel<<<(N + 15) / 16, TPB, 0, stream>>>(csr, offs, h1p, dinv, b1, h2p, N);
    gather2_kernel<<<(N + 15) / 16, TPB, 0, stream>>>(csr, offs, h2p, dinv, a2, N);
    final_kernel<<<(N + 255) / 256, TPB, 0, stream>>>(a2, W2, b2, batch, out, N);
}

// Round 4
// 562.203 us; speedup vs baseline: 10.0788x; 1.0859x over previous
//
#include <hip/hip_runtime.h>
#include <hip/hip_bf16.h>

// 2-layer GCN, CSR-gather, bf16 gather payloads, gemm hidden under the atomic pass.
//   K1: [gemm1 blocks ∥ rank blocks]  -- rank[e]=atomicAdd(deg[col],1) is atomic-rate
//       bound (~25K atomics/us, 32B HBM write-through each; R1-R3 measured) and uses
//       no VALU/BW, so x@W1 rides along for free.  h1 written fp32 UNSCALED.
//   K2-K4: scan(deg) -> offs ; dinv = rsqrt(deg+1)
//   K5: [fill blocks ∥ scale blocks]  -- csr[offs[c]+rank[e]]=row[e] (atomic-free);
//       h1p = bf16(dinv*h1)
//   K6: h2p = bf16(dinv*relu(dinv*(gather(h1p)+self)+b1))
//   K7: a2  = dinv*(gather(h2p)+self)            (fp32)
//   K8: out = pool(a2@W2+b2) over sorted batch, run-accumulated, ~205K atomics

#define TPB 256

__device__ __forceinline__ float bf2f(unsigned short u) {
    union { unsigned int i; float f; } v; v.i = ((unsigned int)u) << 16; return v.f;
}
__device__ __forceinline__ unsigned short f2bf(float f) {
    union { float f; unsigned int i; } v; v.f = f;
    unsigned int r = v.i + 0x7fff + ((v.i >> 16) & 1);   // RNE
    return (unsigned short)(r >> 16);
}

// K1: heterogeneous gemm ∥ rank
__global__ __launch_bounds__(TPB) void gemm_rank_kernel(
        const float* __restrict__ x, const float* __restrict__ W1,
        float* __restrict__ h1, int N,
        const int* __restrict__ col, int* __restrict__ deg,
        unsigned short* __restrict__ rank, int E, int nbGemm) {
    if ((int)blockIdx.x >= nbGemm) {
        int e = ((int)blockIdx.x - nbGemm) * TPB + threadIdx.x;
        if (e < E) rank[e] = (unsigned short)atomicAdd(&deg[col[e]], 1);
        return;
    }
    int n = blockIdx.x * TPB + threadIdx.x;
    if (n >= N) return;
    const float4* xr = (const float4*)(x + (size_t)n * 128);
    float acc[16];
#pragma unroll
    for (int k = 0; k < 16; ++k) acc[k] = 0.f;
#pragma unroll 1
    for (int g = 0; g < 8; ++g) {            // 16 cols of x per group
        float4 v0 = xr[g * 4 + 0], v1 = xr[g * 4 + 1];
        float4 v2 = xr[g * 4 + 2], v3 = xr[g * 4 + 3];
        float xv[16] = {v0.x, v0.y, v0.z, v0.w, v1.x, v1.y, v1.z, v1.w,
                        v2.x, v2.y, v2.z, v2.w, v3.x, v3.y, v3.z, v3.w};
#pragma unroll
        for (int cc = 0; cc < 16; ++cc) {
            const float4* w4 = (const float4*)(W1 + (size_t)(g * 16 + cc) * 16);
            float4 wa = w4[0], wb = w4[1], wc = w4[2], wd = w4[3];
            float xc = xv[cc];
            acc[0]  = fmaf(xc, wa.x, acc[0]);  acc[1]  = fmaf(xc, wa.y, acc[1]);
            acc[2]  = fmaf(xc, wa.z, acc[2]);  acc[3]  = fmaf(xc, wa.w, acc[3]);
            acc[4]  = fmaf(xc, wb.x, acc[4]);  acc[5]  = fmaf(xc, wb.y, acc[5]);
            acc[6]  = fmaf(xc, wb.z, acc[6]);  acc[7]  = fmaf(xc, wb.w, acc[7]);
            acc[8]  = fmaf(xc, wc.x, acc[8]);  acc[9]  = fmaf(xc, wc.y, acc[9]);
            acc[10] = fmaf(xc, wc.z, acc[10]); acc[11] = fmaf(xc, wc.w, acc[11]);
            acc[12] = fmaf(xc, wd.x, acc[12]); acc[13] = fmaf(xc, wd.y, acc[13]);
            acc[14] = fmaf(xc, wd.z, acc[14]); acc[15] = fmaf(xc, wd.w, acc[15]);
        }
    }
    float4* o = (float4*)(h1 + (size_t)n * 16);
    o[0] = make_float4(acc[0], acc[1], acc[2], acc[3]);
    o[1] = make_float4(acc[4], acc[5], acc[6], acc[7]);
    o[2] = make_float4(acc[8], acc[9], acc[10], acc[11]);
    o[3] = make_float4(acc[12], acc[13], acc[14], acc[15]);
}

// K2: block-level exclusive scan of deg; bsum[b] = block total
__global__ __launch_bounds__(TPB) void scan1_kernel(const int* __restrict__ deg,
                                                    int* __restrict__ offs,
                                                    int* __restrict__ bsum, int N) {
    __shared__ int s[TPB];
    int t = threadIdx.x;
    int i = blockIdx.x * TPB + t;
    int d = (i < N) ? deg[i] : 0;
    s[t] = d; __syncthreads();
    for (int off = 1; off < TPB; off <<= 1) {
        int v = (t >= off) ? s[t - off] : 0;
        __syncthreads();
        s[t] += v;
        __syncthreads();
    }
    if (i < N) offs[i] = s[t] - d;
    if (t == TPB - 1) bsum[blockIdx.x] = s[t];
}

// K3: single-block exclusive scan of block sums (nb <= 1024)
__global__ __launch_bounds__(1024) void scan2_kernel(int* __restrict__ bsum, int nb) {
    __shared__ int s[1024];
    int t = threadIdx.x;
    int v = (t < nb) ? bsum[t] : 0;
    s[t] = v; __syncthreads();
    for (int off = 1; off < 1024; off <<= 1) {
        int u = (t >= off) ? s[t - off] : 0;
        __syncthreads();
        s[t] += u;
        __syncthreads();
    }
    if (t < nb) bsum[t] = s[t] - v;
}

// K4: finalize offsets, compute dinv
__global__ __launch_bounds__(TPB) void scan3_kernel(int* __restrict__ offs,
                                                    const int* __restrict__ bsum,
                                                    const int* __restrict__ deg,
                                                    float* __restrict__ dinv, int N, int E) {
    int i = blockIdx.x * TPB + threadIdx.x;
    if (i < N) {
        offs[i] += bsum[blockIdx.x];
        dinv[i] = rsqrtf((float)deg[i] + 1.0f);   // +1 = self loop
    }
    if (i == 0) offs[N] = E;
}

// K5: heterogeneous fill ∥ scale
__global__ __launch_bounds__(TPB) void fill_scale_kernel(
        const int* __restrict__ row, const int* __restrict__ col,
        const unsigned short* __restrict__ rank, const int* __restrict__ offs,
        int* __restrict__ csr, int E, int nbFill,
        const float* __restrict__ h1, const float* __restrict__ dinv,
        unsigned short* __restrict__ h1p, int N) {
    if ((int)blockIdx.x < nbFill) {
        int e = blockIdx.x * TPB + threadIdx.x;
        if (e < E) {
            int c = col[e];
            csr[offs[c] + (int)rank[e]] = row[e];
        }
        return;
    }
    int i = ((int)blockIdx.x - nbFill) * TPB + threadIdx.x;   // one thread per 4 feats
    if (i < N * 4) {
        int n = i >> 2;
        float dv = dinv[n];
        float4 v = ((const float4*)h1)[i];
        ((ushort4*)h1p)[i] = make_ushort4(f2bf(v.x * dv), f2bf(v.y * dv),
                                          f2bf(v.z * dv), f2bf(v.w * dv));
    }
}

// K6: h2p[c] = bf16( dinv[c]*relu( dinv[c]*(sum h1p[src] + h1p[c]) + b1 ) )
__global__ __launch_bounds__(TPB) void gather1_kernel(const int* __restrict__ csr,
                                                      const int* __restrict__ offs,
                                                      const unsigned short* __restrict__ h1p,
                                                      const float* __restrict__ dinv,
                                                      const float* __restrict__ b1,
                                                      unsigned short* __restrict__ h2p, int N) {
    int t = threadIdx.x;
    int c = blockIdx.x * 16 + (t >> 4);
    int k = t & 15;
    if (c >= N) return;
    int p1 = offs[c + 1];
    float acc = 0.f;
    for (int p = offs[c]; p < p1; p += 16) {
        int idx = p + k;
        int s = (idx < p1) ? csr[idx] : -1;
#pragma unroll
        for (int j = 0; j < 16; ++j) {
            int sj = __shfl(s, j, 16);
            if (sj >= 0) acc += bf2f(h1p[(size_t)sj * 16 + k]);
        }
    }
    float dc = dinv[c];
    float self = bf2f(h1p[(size_t)c * 16 + k]);
    float a = fmaf(dc, acc + self, b1[k]);
    h2p[(size_t)c * 16 + k] = f2bf(dc * fmaxf(a, 0.f));
}

// K7: a2[c] = dinv[c]*(sum h2p[src] + h2p[c])   (fp32 out)
__global__ __launch_bounds__(TPB) void gather2_kernel(const int* __restrict__ csr,
                                                      const int* __restrict__ offs,
                                                      const unsigned short* __restrict__ h2p,
                                                      const float* __restrict__ dinv,
                                                      float* __restrict__ a2, int N) {
    int t = threadIdx.x;
    int c = blockIdx.x * 16 + (t >> 4);
    int k = t & 15;
    if (c >= N) return;
    int p1 = offs[c + 1];
    float acc = 0.f;
    for (int p = offs[c]; p < p1; p += 16) {
        int idx = p + k;
        int s = (idx < p1) ? csr[idx] : -1;
#pragma unroll
        for (int j = 0; j < 16; ++j) {
            int sj = __shfl(s, j, 16);
            if (sj >= 0) acc += bf2f(h2p[(size_t)sj * 16 + k]);
        }
    }
    float self = bf2f(h2p[(size_t)c * 16 + k]);
    a2[(size_t)c * 16 + k] = dinv[c] * (acc + self);
}

// K8: out[g] += a2[n]@W2 + b2, pooled over sorted batch; 64 nodes per wave
__global__ __launch_bounds__(TPB) void final_kernel(const float* __restrict__ a2,
                                                    const float* __restrict__ W2,
                                                    const float* __restrict__ b2,
                                                    const int* __restrict__ batch,
                                                    float* __restrict__ out, int N) {
    __shared__ float w2s[16 * 64];
    int t = threadIdx.x;
    for (int i = t; i < 16 * 64; i += TPB) w2s[i] = W2[i];
    __syncthreads();

    int wave = t >> 6, lane = t & 63;
    int n0 = blockIdx.x * 256 + wave * 64;
    float b2k = b2[lane];
    int g_cur = -1;
    float acc = 0.f;
    for (int i = 0; i < 64; ++i) {
        int n = n0 + i;
        if (n >= N) break;
        const float* ar = a2 + (size_t)n * 16;
        float val = b2k;
#pragma unroll
        for (int j = 0; j < 16; ++j) val = fmaf(ar[j], w2s[j * 64 + lane], val);
        int g = batch[n];
        if (g != g_cur) {
            if (g_cur >= 0) atomicAdd(&out[(size_t)g_cur * 64 + lane], acc);
            acc = 0.f;
            g_cur = g;
        }
        acc += val;
    }
    if (g_cur >= 0) atomicAdd(&out[(size_t)g_cur * 64 + lane], acc);
}

static inline size_t align64(size_t v) { return (v + 63) & ~(size_t)63; }

extern "C" void kernel_launch(void* const* d_in, const int* in_sizes, int n_in,
                              void* d_out, int out_size, void* d_ws, size_t ws_size,
                              hipStream_t stream) {
    const float* x     = (const float*)d_in[0];
    const int*   ei    = (const int*)d_in[1];
    const int*   batch = (const int*)d_in[2];
    const float* W1    = (const float*)d_in[3];
    const float* b1    = (const float*)d_in[4];
    const float* W2    = (const float*)d_in[5];
    const float* b2    = (const float*)d_in[6];

    const int N = in_sizes[0] / 128;
    const int E = in_sizes[1] / 2;
    const int* row = ei;        // edge_index[0]
    const int* col = ei + E;    // edge_index[1]
    const int NB  = (N + TPB - 1) / TPB;     // 782 (<=1024 required by scan2)
    const int NBE = (E + TPB - 1) / TPB;     // 12500

    char* p = (char*)d_ws;
    float*          dinv = (float*)p;          p += align64((size_t)N * 4);
    int*            deg  = (int*)p;            p += align64((size_t)N * 4);
    int*            offs = (int*)p;            p += align64((size_t)(N + 1) * 4);
    int*            bsum = (int*)p;            p += align64(1024 * 4);
    unsigned short* rank = (unsigned short*)p; p += align64((size_t)E * 2);
    int*            csr  = (int*)p;            p += align64((size_t)E * 4);
    float*          h1   = (float*)p;          p += align64((size_t)N * 16 * 4);
    unsigned short* h1p  = (unsigned short*)p; p += align64((size_t)N * 16 * 2);
    unsigned short* h2p  = (unsigned short*)p; p += align64((size_t)N * 16 * 2);
    float*          a2   = h1;                 // h1 dead after fill_scale
    float*          out  = (float*)d_out;

    hipMemsetAsync(deg, 0, (size_t)N * sizeof(int), stream);
    hipMemsetAsync(out, 0, (size_t)out_size * sizeof(float), stream);

    gemm_rank_kernel<<<NB + NBE, TPB, 0, stream>>>(x, W1, h1, N, col, deg, rank, E, NB);
    scan1_kernel<<<NB, TPB, 0, stream>>>(deg, offs, bsum, N);
    scan2_kernel<<<1, 1024, 0, stream>>>(bsum, NB);
    scan3_kernel<<<NB, TPB, 0, stream>>>(offs, bsum, deg, dinv, N, E);
    fill_scale_kernel<<<NBE + (N * 4 + TPB - 1) / TPB, TPB, 0, stream>>>(
        row, col, rank, offs, csr, E, NBE, h1, dinv, h1p, N);
    gather1_kernel<<<(N + 15) / 16, TPB, 0, stream>>>(csr, offs, h1p, dinv, b1, h2p, N);
    gather2_kernel<<<(N + 15) / 16, TPB, 0, stream>>>(csr, offs, h2p, dinv, a2, N);
    final_kernel<<<(N + 255) / 256, TPB, 0, stream>>>(a2, W2, b2, batch, out, N);
}

// Round 5
// 504.419 us; speedup vs baseline: 11.2334x; 1.1146x over previous
//
#include <hip/hip_runtime.h>
#include <hip/hip_bf16.h>

// 2-layer GCN, CSR-gather, bf16 gather payloads.
//   K1: [rank blocks FIRST ∥ gemm blocks]  -- rank[e]=atomicAdd(deg[col],1) is
//       atomic-rate bound (~25K/us, 32B HBM write-through each; R1-R4 measured).
//       Rank-first so short atomic blocks churn while gemm rides underneath.
//       gemm: W1 in LDS (broadcast ds_read), 1 thread/node, h1 fp32 unscaled.
//   K2-K4: scan(deg) -> offs ; dinv = rsqrt(deg+1)
//   K5: [fill ∥ scale]: csr[offs[c]+rank[e]]=row[e] ; h1p = bf16(dinv*h1)
//   K6: h2p = bf16(dinv*relu(dinv*(gather(h1p)+self)+b1))
//       gather inner: UNCONDITIONAL clamped loads + value-select so 16 scattered
//       loads stay in flight per 16-lane group (R4 lesson: guarded loads serialize
//       on L2/L3 latency).
//   K7: a2 = dinv*(gather(h2p)+self)  (fp32)
//   K8: out = pool(a2@W2+b2) over sorted batch runs

#define TPB 256

__device__ __forceinline__ float bf2f(unsigned short u) {
    union { unsigned int i; float f; } v; v.i = ((unsigned int)u) << 16; return v.f;
}
__device__ __forceinline__ unsigned short f2bf(float f) {
    union { float f; unsigned int i; } v; v.f = f;
    unsigned int r = v.i + 0x7fff + ((v.i >> 16) & 1);   // RNE
    return (unsigned short)(r >> 16);
}

// K1: heterogeneous rank (first) ∥ gemm
__global__ __launch_bounds__(TPB) void rank_gemm_kernel(
        const int* __restrict__ col, int* __restrict__ deg,
        unsigned short* __restrict__ rank, int E, int nbRank,
        const float* __restrict__ x, const float* __restrict__ W1,
        float* __restrict__ h1, int N) {
    if ((int)blockIdx.x < nbRank) {
        int e = blockIdx.x * TPB + threadIdx.x;
        if (e < E) rank[e] = (unsigned short)atomicAdd(&deg[col[e]], 1);
        return;
    }
    __shared__ float w1s[128 * 16];
    int t = threadIdx.x;
    for (int i = t; i < 128 * 16; i += TPB) w1s[i] = W1[i];
    __syncthreads();

    int n = ((int)blockIdx.x - nbRank) * TPB + t;
    if (n >= N) return;
    const float4* xr = (const float4*)(x + (size_t)n * 128);
    float acc[16];
#pragma unroll
    for (int k = 0; k < 16; ++k) acc[k] = 0.f;
#pragma unroll 1
    for (int g = 0; g < 8; ++g) {            // 16 cols of x per group
        float4 v0 = xr[g * 4 + 0], v1 = xr[g * 4 + 1];
        float4 v2 = xr[g * 4 + 2], v3 = xr[g * 4 + 3];
        float xv[16] = {v0.x, v0.y, v0.z, v0.w, v1.x, v1.y, v1.z, v1.w,
                        v2.x, v2.y, v2.z, v2.w, v3.x, v3.y, v3.z, v3.w};
#pragma unroll
        for (int cc = 0; cc < 16; ++cc) {
            const float4* w4 = (const float4*)&w1s[(size_t)(g * 16 + cc) * 16];
            float4 wa = w4[0], wb = w4[1], wc = w4[2], wd = w4[3];
            float xc = xv[cc];
            acc[0]  = fmaf(xc, wa.x, acc[0]);  acc[1]  = fmaf(xc, wa.y, acc[1]);
            acc[2]  = fmaf(xc, wa.z, acc[2]);  acc[3]  = fmaf(xc, wa.w, acc[3]);
            acc[4]  = fmaf(xc, wb.x, acc[4]);  acc[5]  = fmaf(xc, wb.y, acc[5]);
            acc[6]  = fmaf(xc, wb.z, acc[6]);  acc[7]  = fmaf(xc, wb.w, acc[7]);
            acc[8]  = fmaf(xc, wc.x, acc[8]);  acc[9]  = fmaf(xc, wc.y, acc[9]);
            acc[10] = fmaf(xc, wc.z, acc[10]); acc[11] = fmaf(xc, wc.w, acc[11]);
            acc[12] = fmaf(xc, wd.x, acc[12]); acc[13] = fmaf(xc, wd.y, acc[13]);
            acc[14] = fmaf(xc, wd.z, acc[14]); acc[15] = fmaf(xc, wd.w, acc[15]);
        }
    }
    float4* o = (float4*)(h1 + (size_t)n * 16);
    o[0] = make_float4(acc[0], acc[1], acc[2], acc[3]);
    o[1] = make_float4(acc[4], acc[5], acc[6], acc[7]);
    o[2] = make_float4(acc[8], acc[9], acc[10], acc[11]);
    o[3] = make_float4(acc[12], acc[13], acc[14], acc[15]);
}

// K2: block-level exclusive scan of deg; bsum[b] = block total
__global__ __launch_bounds__(TPB) void scan1_kernel(const int* __restrict__ deg,
                                                    int* __restrict__ offs,
                                                    int* __restrict__ bsum, int N) {
    __shared__ int s[TPB];
    int t = threadIdx.x;
    int i = blockIdx.x * TPB + t;
    int d = (i < N) ? deg[i] : 0;
    s[t] = d; __syncthreads();
    for (int off = 1; off < TPB; off <<= 1) {
        int v = (t >= off) ? s[t - off] : 0;
        __syncthreads();
        s[t] += v;
        __syncthreads();
    }
    if (i < N) offs[i] = s[t] - d;
    if (t == TPB - 1) bsum[blockIdx.x] = s[t];
}

// K3: single-block exclusive scan of block sums (nb <= 1024)
__global__ __launch_bounds__(1024) void scan2_kernel(int* __restrict__ bsum, int nb) {
    __shared__ int s[1024];
    int t = threadIdx.x;
    int v = (t < nb) ? bsum[t] : 0;
    s[t] = v; __syncthreads();
    for (int off = 1; off < 1024; off <<= 1) {
        int u = (t >= off) ? s[t - off] : 0;
        __syncthreads();
        s[t] += u;
        __syncthreads();
    }
    if (t < nb) bsum[t] = s[t] - v;
}

// K4: finalize offsets, compute dinv
__global__ __launch_bounds__(TPB) void scan3_kernel(int* __restrict__ offs,
                                                    const int* __restrict__ bsum,
                                                    const int* __restrict__ deg,
                                                    float* __restrict__ dinv, int N, int E) {
    int i = blockIdx.x * TPB + threadIdx.x;
    if (i < N) {
        offs[i] += bsum[blockIdx.x];
        dinv[i] = rsqrtf((float)deg[i] + 1.0f);   // +1 = self loop
    }
    if (i == 0) offs[N] = E;
}

// K5: heterogeneous fill ∥ scale
__global__ __launch_bounds__(TPB) void fill_scale_kernel(
        const int* __restrict__ row, const int* __restrict__ col,
        const unsigned short* __restrict__ rank, const int* __restrict__ offs,
        int* __restrict__ csr, int E, int nbFill,
        const float* __restrict__ h1, const float* __restrict__ dinv,
        unsigned short* __restrict__ h1p, int N) {
    if ((int)blockIdx.x < nbFill) {
        int e = blockIdx.x * TPB + threadIdx.x;
        if (e < E) {
            int c = col[e];
            csr[offs[c] + (int)rank[e]] = row[e];
        }
        return;
    }
    int i = ((int)blockIdx.x - nbFill) * TPB + threadIdx.x;   // one thread per 4 feats
    if (i < N * 4) {
        int n = i >> 2;
        float dv = dinv[n];
        float4 v = ((const float4*)h1)[i];
        ((ushort4*)h1p)[i] = make_ushort4(f2bf(v.x * dv), f2bf(v.y * dv),
                                          f2bf(v.z * dv), f2bf(v.w * dv));
    }
}

// K6: h2p[c] = bf16( dinv[c]*relu( dinv[c]*(sum h1p[src] + h1p[c]) + b1 ) )
// Unconditional clamped loads; select on value -> 16 loads in flight per group.
__global__ __launch_bounds__(TPB) void gather1_kernel(const int* __restrict__ csr,
                                                      const int* __restrict__ offs,
                                                      const unsigned short* __restrict__ h1p,
                                                      const float* __restrict__ dinv,
                                                      const float* __restrict__ b1,
                                                      unsigned short* __restrict__ h2p, int N) {
    int t = threadIdx.x;
    int c = blockIdx.x * 16 + (t >> 4);
    int k = t & 15;
    if (c >= N) return;
    int p0 = offs[c], p1 = offs[c + 1];
    float acc = 0.f;
    for (int p = p0; p < p1; p += 16) {
        int idx = p + k;
        int s = csr[min(idx, p1 - 1)];
        int rem = p1 - p;                    // uniform within the 16-lane group
        float v[16];
#pragma unroll
        for (int j = 0; j < 16; ++j) {
            int sj = __shfl(s, j, 16);
            v[j] = bf2f(h1p[(size_t)sj * 16 + k]);
        }
#pragma unroll
        for (int j = 0; j < 16; ++j) acc += (j < rem) ? v[j] : 0.f;
    }
    float dc = dinv[c];
    float self = bf2f(h1p[(size_t)c * 16 + k]);
    float a = fmaf(dc, acc + self, b1[k]);
    h2p[(size_t)c * 16 + k] = f2bf(dc * fmaxf(a, 0.f));
}

// K7: a2[c] = dinv[c]*(sum h2p[src] + h2p[c])   (fp32 out)
__global__ __launch_bounds__(TPB) void gather2_kernel(const int* __restrict__ csr,
                                                      const int* __restrict__ offs,
                                                      const unsigned short* __restrict__ h2p,
                                                      const float* __restrict__ dinv,
                                                      float* __restrict__ a2, int N) {
    int t = threadIdx.x;
    int c = blockIdx.x * 16 + (t >> 4);
    int k = t & 15;
    if (c >= N) return;
    int p0 = offs[c], p1 = offs[c + 1];
    float acc = 0.f;
    for (int p = p0; p < p1; p += 16) {
        int idx = p + k;
        int s = csr[min(idx, p1 - 1)];
        int rem = p1 - p;
        float v[16];
#pragma unroll
        for (int j = 0; j < 16; ++j) {
            int sj = __shfl(s, j, 16);
            v[j] = bf2f(h2p[(size_t)sj * 16 + k]);
        }
#pragma unroll
        for (int j = 0; j < 16; ++j) acc += (j < rem) ? v[j] : 0.f;
    }
    float self = bf2f(h2p[(size_t)c * 16 + k]);
    a2[(size_t)c * 16 + k] = dinv[c] * (acc + self);
}

// K8: out[g] += a2[n]@W2 + b2, pooled over sorted batch; 64 nodes per wave
__global__ __launch_bounds__(TPB) void final_kernel(const float* __restrict__ a2,
                                                    const float* __restrict__ W2,
                                                    const float* __restrict__ b2,
                                                    const int* __restrict__ batch,
                                                    float* __restrict__ out, int N) {
    __shared__ float w2s[16 * 64];
    int t = threadIdx.x;
    for (int i = t; i < 16 * 64; i += TPB) w2s[i] = W2[i];
    __syncthreads();

    int wave = t >> 6, lane = t & 63;
    int n0 = blockIdx.x * 256 + wave * 64;
    float b2k = b2[lane];
    int g_cur = -1;
    float acc = 0.f;
    for (int i = 0; i < 64; ++i) {
        int n = n0 + i;
        if (n >= N) break;
        const float* ar = a2 + (size_t)n * 16;
        float val = b2k;
#pragma unroll
        for (int j = 0; j < 16; ++j) val = fmaf(ar[j], w2s[j * 64 + lane], val);
        int g = batch[n];
        if (g != g_cur) {
            if (g_cur >= 0) atomicAdd(&out[(size_t)g_cur * 64 + lane], acc);
            acc = 0.f;
            g_cur = g;
        }
        acc += val;
    }
    if (g_cur >= 0) atomicAdd(&out[(size_t)g_cur * 64 + lane], acc);
}

static inline size_t align64(size_t v) { return (v + 63) & ~(size_t)63; }

extern "C" void kernel_launch(void* const* d_in, const int* in_sizes, int n_in,
                              void* d_out, int out_size, void* d_ws, size_t ws_size,
                              hipStream_t stream) {
    const float* x     = (const float*)d_in[0];
    const int*   ei    = (const int*)d_in[1];
    const int*   batch = (const int*)d_in[2];
    const float* W1    = (const float*)d_in[3];
    const float* b1    = (const float*)d_in[4];
    const float* W2    = (const float*)d_in[5];
    const float* b2    = (const float*)d_in[6];

    const int N = in_sizes[0] / 128;
    const int E = in_sizes[1] / 2;
    const int* row = ei;        // edge_index[0]
    const int* col = ei + E;    // edge_index[1]
    const int NB  = (N + TPB - 1) / TPB;     // 782 (<=1024 required by scan2)
    const int NBE = (E + TPB - 1) / TPB;     // 12500

    char* p = (char*)d_ws;
    float*          dinv = (float*)p;          p += align64((size_t)N * 4);
    int*            deg  = (int*)p;            p += align64((size_t)N * 4);
    int*            offs = (int*)p;            p += align64((size_t)(N + 1) * 4);
    int*            bsum = (int*)p;            p += align64(1024 * 4);
    unsigned short* rank = (unsigned short*)p; p += align64((size_t)E * 2);
    int*            csr  = (int*)p;            p += align64((size_t)E * 4);
    float*          h1   = (float*)p;          p += align64((size_t)N * 16 * 4);
    unsigned short* h1p  = (unsigned short*)p; p += align64((size_t)N * 16 * 2);
    unsigned short* h2p  = (unsigned short*)p; p += align64((size_t)N * 16 * 2);
    float*          a2   = h1;                 // h1 dead after fill_scale
    float*          out  = (float*)d_out;

    hipMemsetAsync(deg, 0, (size_t)N * sizeof(int), stream);
    hipMemsetAsync(out, 0, (size_t)out_size * sizeof(float), stream);

    rank_gemm_kernel<<<NBE + NB, TPB, 0, stream>>>(col, deg, rank, E, NBE, x, W1, h1, N);
    scan1_kernel<<<NB, TPB, 0, stream>>>(deg, offs, bsum, N);
    scan2_kernel<<<1, 1024, 0, stream>>>(bsum, NB);
    scan3_kernel<<<NB, TPB, 0, stream>>>(offs, bsum, deg, dinv, N, E);
    fill_scale_kernel<<<NBE + (N * 4 + TPB - 1) / TPB, TPB, 0, stream>>>(
        row, col, rank, offs, csr, E, NBE, h1, dinv, h1p, N);
    gather1_kernel<<<(N + 15) / 16, TPB, 0, stream>>>(csr, offs, h1p, dinv, b1, h2p, N);
    gather2_kernel<<<(N + 15) / 16, TPB, 0, stream>>>(csr, offs, h2p, dinv, a2, N);
    final_kernel<<<(N + 255) / 256, TPB, 0, stream>>>(a2, W2, b2, batch, out, N);
}

// Round 6
// 398.915 us; speedup vs baseline: 14.2044x; 1.2645x over previous
//
#include <hip/hip_runtime.h>

// 2-layer GCN, CSR-gather, bf16 payloads, ZERO global atomics in the CSR build.
// R1-R5 lesson: global atomicAdd ~25K ops/us device-wide (32B HBM write-through
// per op) regardless of contention -> any per-edge global atomic pass costs
// >=128us. Replace rank+fill with a two-level bucket counting sort:
//   S1a: per-block LDS histogram over 196 buckets (col>>10) -> counts[bk][blk]
//   scan: generic exclusive scan over flattened counts (196*782)
//   S1c ∥ gemm (block-interleaved even/odd): scatter edges to bucket-major
//        bucketed[] via LDS cursors; gemm x@W1 -> h1 (fp32, unscaled)
//   S2: one block per bucket: exact counting sort by node (LDS hist+scan+cursors),
//       emits csr, offs, dinv, and h1p = bf16(dinv*h1)  (coalesced writes)
//   gather1: h2p = bf16(dinv*relu(dinv*(sum h1p[src]+self)+b1))  (clamped
//            unconditional loads, R5 lesson)
//   gather2: a2 = dinv*(sum h2p[src]+self)
//   final:  out[g] += a2@W2 + b2 pooled over sorted batch runs

#define TPB 256
#define CHUNK 4096          // edges per stage-1 block
#define BK_SHIFT 10
#define NPB 1024            // nodes per bucket = 1 << BK_SHIFT

__device__ __forceinline__ float bf2f(unsigned short u) {
    union { unsigned int i; float f; } v; v.i = ((unsigned int)u) << 16; return v.f;
}
__device__ __forceinline__ unsigned short f2bf(float f) {
    union { float f; unsigned int i; } v; v.f = f;
    unsigned int r = v.i + 0x7fff + ((v.i >> 16) & 1);   // RNE
    return (unsigned short)(r >> 16);
}

// S1a: counts[bk*nblk + blk] = #edges in block blk with col>>10 == bk
__global__ __launch_bounds__(TPB) void hist_kernel(const int* __restrict__ col,
                                                   int* __restrict__ counts,
                                                   int E, int nblk, int nbuck) {
    __shared__ int hist[256];                 // nbuck <= 256
    int t = threadIdx.x;
    if (t < nbuck) hist[t] = 0;
    __syncthreads();
    int e0 = blockIdx.x * CHUNK;
    for (int i = t; i < CHUNK; i += TPB) {
        int e = e0 + i;
        if (e < E) atomicAdd(&hist[col[e] >> BK_SHIFT], 1);   // LDS atomic
    }
    __syncthreads();
    if (t < nbuck) counts[t * nblk + blockIdx.x] = hist[t];
}

// generic exclusive scan, 3 kernels (in-place safe: each elem read once, LDS scan)
__global__ __launch_bounds__(TPB) void scan1_kernel(const int* __restrict__ in,
                                                    int* __restrict__ out,
                                                    int* __restrict__ bsum, int L) {
    __shared__ int s[TPB];
    int t = threadIdx.x;
    int i = blockIdx.x * TPB + t;
    int d = (i < L) ? in[i] : 0;
    s[t] = d; __syncthreads();
    for (int off = 1; off < TPB; off <<= 1) {
        int v = (t >= off) ? s[t - off] : 0;
        __syncthreads();
        s[t] += v;
        __syncthreads();
    }
    if (i < L) out[i] = s[t] - d;
    if (t == TPB - 1) bsum[blockIdx.x] = s[t];
}

__global__ __launch_bounds__(1024) void scan2_kernel(int* __restrict__ bsum, int nb) {
    __shared__ int s[1024];
    int t = threadIdx.x;
    int v = (t < nb) ? bsum[t] : 0;
    s[t] = v; __syncthreads();
    for (int off = 1; off < 1024; off <<= 1) {
        int u = (t >= off) ? s[t - off] : 0;
        __syncthreads();
        s[t] += u;
        __syncthreads();
    }
    if (t < nb) bsum[t] = s[t] - v;
}

__global__ __launch_bounds__(TPB) void scan3g_kernel(int* __restrict__ out,
                                                     const int* __restrict__ bsum, int L) {
    int i = blockIdx.x * TPB + threadIdx.x;
    if (i < L) out[i] += bsum[blockIdx.x];
}

// S1c ∥ gemm, interleaved even/odd so both are co-resident (R5 lesson:
// concatenated heterogeneous grids serialize).
__global__ __launch_bounds__(TPB) void s1c_gemm_kernel(
        const int* __restrict__ row, const int* __restrict__ col,
        const int* __restrict__ cbase, int E, int nblk, int nbuck,
        int2* __restrict__ bucketed,
        const float* __restrict__ x, const float* __restrict__ W1,
        float* __restrict__ h1, int N, int nbg) {
    __shared__ int cur[256];
    __shared__ float w1s[128 * 16];
    int b = (int)blockIdx.x, t = threadIdx.x;
    int M = min(nblk, nbg);
    int role, id;
    if (b < 2 * M) { role = b & 1; id = b >> 1; }
    else           { role = (nblk > nbg) ? 0 : 1; id = b - M; }

    if (role == 0) {                         // scatter to bucket-major
        if (t < nbuck) cur[t] = cbase[t * nblk + id];
        __syncthreads();
        int e0 = id * CHUNK;
        for (int i = t; i < CHUNK; i += TPB) {
            int e = e0 + i;
            if (e < E) {
                int c = col[e];
                int pos = atomicAdd(&cur[c >> BK_SHIFT], 1);   // LDS atomic
                bucketed[pos] = make_int2(c, row[e]);
            }
        }
        return;
    }
    // gemm: h1[n] = x[n] @ W1, one thread per node, W1 in LDS
    for (int i = t; i < 128 * 16; i += TPB) w1s[i] = W1[i];
    __syncthreads();
    int n = id * TPB + t;
    if (n >= N) return;
    const float4* xr = (const float4*)(x + (size_t)n * 128);
    float acc[16];
#pragma unroll
    for (int k = 0; k < 16; ++k) acc[k] = 0.f;
#pragma unroll 1
    for (int g = 0; g < 8; ++g) {
        float4 v0 = xr[g * 4 + 0], v1 = xr[g * 4 + 1];
        float4 v2 = xr[g * 4 + 2], v3 = xr[g * 4 + 3];
        float xv[16] = {v0.x, v0.y, v0.z, v0.w, v1.x, v1.y, v1.z, v1.w,
                        v2.x, v2.y, v2.z, v2.w, v3.x, v3.y, v3.z, v3.w};
#pragma unroll
        for (int cc = 0; cc < 16; ++cc) {
            const float4* w4 = (const float4*)&w1s[(g * 16 + cc) * 16];
            float4 wa = w4[0], wb = w4[1], wc = w4[2], wd = w4[3];
            float xc = xv[cc];
            acc[0]  = fmaf(xc, wa.x, acc[0]);  acc[1]  = fmaf(xc, wa.y, acc[1]);
            acc[2]  = fmaf(xc, wa.z, acc[2]);  acc[3]  = fmaf(xc, wa.w, acc[3]);
            acc[4]  = fmaf(xc, wb.x, acc[4]);  acc[5]  = fmaf(xc, wb.y, acc[5]);
            acc[6]  = fmaf(xc, wb.z, acc[6]);  acc[7]  = fmaf(xc, wb.w, acc[7]);
            acc[8]  = fmaf(xc, wc.x, acc[8]);  acc[9]  = fmaf(xc, wc.y, acc[9]);
            acc[10] = fmaf(xc, wc.z, acc[10]); acc[11] = fmaf(xc, wc.w, acc[11]);
            acc[12] = fmaf(xc, wd.x, acc[12]); acc[13] = fmaf(xc, wd.y, acc[13]);
            acc[14] = fmaf(xc, wd.z, acc[14]); acc[15] = fmaf(xc, wd.w, acc[15]);
        }
    }
    float4* o = (float4*)(h1 + (size_t)n * 16);
    o[0] = make_float4(acc[0], acc[1], acc[2], acc[3]);
    o[1] = make_float4(acc[4], acc[5], acc[6], acc[7]);
    o[2] = make_float4(acc[8], acc[9], acc[10], acc[11]);
    o[3] = make_float4(acc[12], acc[13], acc[14], acc[15]);
}

// S2: one block per bucket. Counting sort by exact node, emit csr/offs/dinv and
// h1p = bf16(dinv*h1). All global writes coalesced except csr (L2-local window).
__global__ __launch_bounds__(TPB) void sort_kernel(
        const int2* __restrict__ bucketed, const int* __restrict__ cbase,
        int E, int nblk, int nbuck,
        int* __restrict__ csr, int* __restrict__ offs, float* __restrict__ dinv,
        const float* __restrict__ h1, unsigned short* __restrict__ h1p, int N) {
    __shared__ int lhist[NPB];
    __shared__ int part[TPB];
    __shared__ float sdinv[NPB];
    int bk = blockIdx.x, t = threadIdx.x;
    int n0 = bk << BK_SHIFT;
    int n1 = min(n0 + NPB, N);
    int e0 = cbase[bk * nblk];
    int e1 = (bk + 1 < nbuck) ? cbase[(bk + 1) * nblk] : E;

    for (int i = t; i < NPB; i += TPB) lhist[i] = 0;
    __syncthreads();
    for (int i = e0 + t; i < e1; i += TPB)
        atomicAdd(&lhist[bucketed[i].x & (NPB - 1)], 1);       // LDS atomic
    __syncthreads();

    int base = t * 4;
    int c0 = lhist[base], c1 = lhist[base + 1], c2 = lhist[base + 2], c3 = lhist[base + 3];
    int s = c0 + c1 + c2 + c3;
    part[t] = s;
    __syncthreads();
    for (int off = 1; off < TPB; off <<= 1) {
        int v = (t >= off) ? part[t - off] : 0;
        __syncthreads();
        part[t] += v;
        __syncthreads();
    }
    int o0 = e0 + part[t] - s;
    int o1 = o0 + c0, o2 = o1 + c1, o3 = o2 + c2;
    lhist[base] = o0; lhist[base + 1] = o1; lhist[base + 2] = o2; lhist[base + 3] = o3;
    sdinv[base]     = rsqrtf((float)c0 + 1.0f);
    sdinv[base + 1] = rsqrtf((float)c1 + 1.0f);
    sdinv[base + 2] = rsqrtf((float)c2 + 1.0f);
    sdinv[base + 3] = rsqrtf((float)c3 + 1.0f);
    int n = n0 + base;
    if (n + 0 < N) { offs[n + 0] = o0; dinv[n + 0] = sdinv[base]; }
    if (n + 1 < N) { offs[n + 1] = o1; dinv[n + 1] = sdinv[base + 1]; }
    if (n + 2 < N) { offs[n + 2] = o2; dinv[n + 2] = sdinv[base + 2]; }
    if (n + 3 < N) { offs[n + 3] = o3; dinv[n + 3] = sdinv[base + 3]; }
    __syncthreads();

    for (int i = e0 + t; i < e1; i += TPB) {
        int2 cr = bucketed[i];
        int pos = atomicAdd(&lhist[cr.x & (NPB - 1)], 1);      // LDS atomic
        csr[pos] = cr.y;
    }
    // h1 -> h1p (bf16, dinv-scaled) for this bucket's nodes
    int nq = (n1 - n0) * 4;
    for (int i = t; i < nq; i += TPB) {
        float dv = sdinv[i >> 2];
        float4 v = ((const float4*)h1)[(size_t)n0 * 4 + i];
        ((ushort4*)h1p)[(size_t)n0 * 4 + i] =
            make_ushort4(f2bf(v.x * dv), f2bf(v.y * dv), f2bf(v.z * dv), f2bf(v.w * dv));
    }
    if (bk == 0 && t == 0) offs[N] = E;
}

// gather1: h2p[c] = bf16( dinv[c]*relu( dinv[c]*(sum h1p[src] + h1p[c]) + b1 ) )
__global__ __launch_bounds__(TPB) void gather1_kernel(const int* __restrict__ csr,
                                                      const int* __restrict__ offs,
                                                      const unsigned short* __restrict__ h1p,
                                                      const float* __restrict__ dinv,
                                                      const float* __restrict__ b1,
                                                      unsigned short* __restrict__ h2p, int N) {
    int t = threadIdx.x;
    int c = blockIdx.x * 16 + (t >> 4);
    int k = t & 15;
    if (c >= N) return;
    int p0 = offs[c], p1 = offs[c + 1];
    float acc = 0.f;
    for (int p = p0; p < p1; p += 16) {
        int idx = p + k;
        int s = csr[min(idx, p1 - 1)];
        int rem = p1 - p;
        float v[16];
#pragma unroll
        for (int j = 0; j < 16; ++j) {
            int sj = __shfl(s, j, 16);
            v[j] = bf2f(h1p[(size_t)sj * 16 + k]);
        }
#pragma unroll
        for (int j = 0; j < 16; ++j) acc += (j < rem) ? v[j] : 0.f;
    }
    float dc = dinv[c];
    float self = bf2f(h1p[(size_t)c * 16 + k]);
    float a = fmaf(dc, acc + self, b1[k]);
    h2p[(size_t)c * 16 + k] = f2bf(dc * fmaxf(a, 0.f));
}

// gather2: a2[c] = dinv[c]*(sum h2p[src] + h2p[c])
__global__ __launch_bounds__(TPB) void gather2_kernel(const int* __restrict__ csr,
                                                      const int* __restrict__ offs,
                                                      const unsigned short* __restrict__ h2p,
                                                      const float* __restrict__ dinv,
                                                      float* __restrict__ a2, int N) {
    int t = threadIdx.x;
    int c = blockIdx.x * 16 + (t >> 4);
    int k = t & 15;
    if (c >= N) return;
    int p0 = offs[c], p1 = offs[c + 1];
    float acc = 0.f;
    for (int p = p0; p < p1; p += 16) {
        int idx = p + k;
        int s = csr[min(idx, p1 - 1)];
        int rem = p1 - p;
        float v[16];
#pragma unroll
        for (int j = 0; j < 16; ++j) {
            int sj = __shfl(s, j, 16);
            v[j] = bf2f(h2p[(size_t)sj * 16 + k]);
        }
#pragma unroll
        for (int j = 0; j < 16; ++j) acc += (j < rem) ? v[j] : 0.f;
    }
    float self = bf2f(h2p[(size_t)c * 16 + k]);
    a2[(size_t)c * 16 + k] = dinv[c] * (acc + self);
}

// final: out[g] += a2[n]@W2 + b2, pooled over sorted batch; 64 nodes per wave
__global__ __launch_bounds__(TPB) void final_kernel(const float* __restrict__ a2,
                                                    const float* __restrict__ W2,
                                                    const float* __restrict__ b2,
                                                    const int* __restrict__ batch,
                                                    float* __restrict__ out, int N) {
    __shared__ float w2s[16 * 64];
    int t = threadIdx.x;
    for (int i = t; i < 16 * 64; i += TPB) w2s[i] = W2[i];
    __syncthreads();

    int wave = t >> 6, lane = t & 63;
    int n0 = blockIdx.x * 256 + wave * 64;
    float b2k = b2[lane];
    int g_cur = -1;
    float acc = 0.f;
    for (int i = 0; i < 64; ++i) {
        int n = n0 + i;
        if (n >= N) break;
        const float* ar = a2 + (size_t)n * 16;
        float val = b2k;
#pragma unroll
        for (int j = 0; j < 16; ++j) val = fmaf(ar[j], w2s[j * 64 + lane], val);
        int g = batch[n];
        if (g != g_cur) {
            if (g_cur >= 0) atomicAdd(&out[(size_t)g_cur * 64 + lane], acc);
            acc = 0.f;
            g_cur = g;
        }
        acc += val;
    }
    if (g_cur >= 0) atomicAdd(&out[(size_t)g_cur * 64 + lane], acc);
}

static inline size_t align64(size_t v) { return (v + 63) & ~(size_t)63; }

extern "C" void kernel_launch(void* const* d_in, const int* in_sizes, int n_in,
                              void* d_out, int out_size, void* d_ws, size_t ws_size,
                              hipStream_t stream) {
    const float* x     = (const float*)d_in[0];
    const int*   ei    = (const int*)d_in[1];
    const int*   batch = (const int*)d_in[2];
    const float* W1    = (const float*)d_in[3];
    const float* b1    = (const float*)d_in[4];
    const float* W2    = (const float*)d_in[5];
    const float* b2    = (const float*)d_in[6];

    const int N = in_sizes[0] / 128;
    const int E = in_sizes[1] / 2;
    const int* row = ei;        // edge_index[0]
    const int* col = ei + E;    // edge_index[1]

    const int NBLK  = (E + CHUNK - 1) / CHUNK;       // 782
    const int NBUCK = (N + NPB - 1) / NPB;           // 196 (<=256)
    const int L     = NBUCK * NBLK;                  // 153272
    const int NBS   = (L + TPB - 1) / TPB;           // 599 (<=1024)
    const int NBG   = (N + TPB - 1) / TPB;           // 782

    char* p = (char*)d_ws;
    int*            counts   = (int*)p;            p += align64((size_t)L * 4);
    int*            bsum     = (int*)p;            p += align64(1024 * 4);
    int2*           bucketed = (int2*)p;           p += align64((size_t)E * 8);
    int*            csr      = (int*)p;            p += align64((size_t)E * 4);
    int*            offs     = (int*)p;            p += align64((size_t)(N + 1) * 4);
    float*          dinv     = (float*)p;          p += align64((size_t)N * 4);
    float*          h1       = (float*)p;          p += align64((size_t)N * 16 * 4);
    unsigned short* h1p      = (unsigned short*)p; p += align64((size_t)N * 16 * 2);
    unsigned short* h2p      = (unsigned short*)p; p += align64((size_t)N * 16 * 2);
    float*          a2       = h1;                 // h1 dead after sort_kernel
    float*          out      = (float*)d_out;

    hipMemsetAsync(out, 0, (size_t)out_size * sizeof(float), stream);

    hist_kernel<<<NBLK, TPB, 0, stream>>>(col, counts, E, NBLK, NBUCK);
    scan1_kernel<<<NBS, TPB, 0, stream>>>(counts, counts, bsum, L);
    scan2_kernel<<<1, 1024, 0, stream>>>(bsum, NBS);
    scan3g_kernel<<<NBS, TPB, 0, stream>>>(counts, bsum, L);
    s1c_gemm_kernel<<<NBLK + NBG, TPB, 0, stream>>>(row, col, counts, E, NBLK, NBUCK,
                                                    bucketed, x, W1, h1, N, NBG);
    sort_kernel<<<NBUCK, TPB, 0, stream>>>(bucketed, counts, E, NBLK, NBUCK,
                                           csr, offs, dinv, h1, h1p, N);
    gather1_kernel<<<(N + 15) / 16, TPB, 0, stream>>>(csr, offs, h1p, dinv, b1, h2p, N);
    gather2_kernel<<<(N + 15) / 16, TPB, 0, stream>>>(csr, offs, h2p, dinv, a2, N);
    final_kernel<<<(N + 255) / 256, TPB, 0, stream>>>(a2, W2, b2, batch, out, N);
}